// Round 14
// baseline (137.976 us; speedup 1.0000x reference)
//
#include <hip/hip_runtime.h>
#include <hip/hip_bf16.h>
#include <math.h>

#define BB 16
#define PP 32768
#define GG 32
#define NC 81
#define BINSHIFT 13
#define NBINS 8192            // 32 KB LDS histogram
#define LOWMASK 0x1FFFu
#define BINBASE 0x3B800000u   // 2^-8 < min possible smx (1/81)
#define CAND_CAP 2048
#define SENT 0x7FFFFFFFu
#define SM_BLOCKS 4096        // backfill: 2x blocks, half tiles each
#define BLK_PER_IMG 256       // 4096 / 16
#define NTILES_BLK 4          // 1024 / 256
#define NEGINF (-3.0e38f)

struct Accs {
  float m[BB]; float l[BB]; float n[BB];
  unsigned tot[BB]; unsigned rowm[BB];
  unsigned tbin[BB]; unsigned rem[BB]; unsigned candcnt[BB];
  unsigned done;
};

__device__ __forceinline__ int bin_of(unsigned bits) {
  int bin = ((int)bits - (int)BINBASE) >> BINSHIFT;
  return bin < 0 ? 0 : (bin > NBINS - 1 ? NBINS - 1 : bin);
}

__global__ void init_kernel(Accs* __restrict__ acc) {
  const int t = threadIdx.x;
  if (t < BB) {
    acc->m[t] = 0.f; acc->l[t] = 0.f; acc->n[t] = 0.f;
    acc->tot[t] = 0u; acc->rowm[t] = 0u; acc->candcnt[t] = 0u;
  }
  if (t == 0) acc->done = 0u;
}

// Round-9 main_kernel body, unchanged except grid decomposition:
// 4096 blocks x 4 tiles (was 2048 x 8) so CUs have queued blocks to
// backfill stalled/retired waves.
__global__ __launch_bounds__(256) void main_kernel(
    const float* __restrict__ pred_boxes,   // (B,P,4)
    const float* __restrict__ conf,         // (B,P,C)
    const float* __restrict__ gt_boxes,     // (B,G,4)
    const int*   __restrict__ gt_labels,    // (B,G)
    float* __restrict__ neg,                // (B,P)
    Accs* __restrict__ acc)
{
  const int tid  = threadIdx.x;
  const int j    = tid & 7;                 // sub-thread within row
  const int rsub = tid >> 3;                // row within tile (0..31)
  const int b    = blockIdx.x / BLK_PER_IMG;
  const int loc  = blockIdx.x % BLK_PER_IMG;
  const int lane = tid & 63;
  const int w    = tid >> 6;

  __shared__ unsigned s_gm[NC + 3];         // label->gt-bitmask table
  __shared__ float pg[4], pl[4];
  __shared__ unsigned pc[4], pr[4];

  // ---- build per-image label-mask table (once per block) ----
  if (tid < NC + 3) s_gm[tid] = 0u;
  __syncthreads();
  if (tid < GG) atomicOr(&s_gm[gt_labels[b * GG + tid]], 1u << tid);
  __syncthreads();

  // ---- gt boxes in registers (4 per thread, j-layout) ----
  const float4* gtb = ((const float4*)gt_boxes) + b * GG;
  const float4 gA = gtb[j];
  const float4 gB = gtb[j + 8];
  const float4 gC = gtb[j + 16];
  const float4 gD = gtb[j + 24];
  const float abA = fmaxf(gA.z - gA.x, 0.f) * fmaxf(gA.w - gA.y, 0.f);
  const float abB = fmaxf(gB.z - gB.x, 0.f) * fmaxf(gB.w - gB.y, 0.f);
  const float abC = fmaxf(gC.z - gC.x, 0.f) * fmaxf(gC.w - gC.y, 0.f);
  const float abD = fmaxf(gD.z - gD.x, 0.f) * fmaxf(gD.w - gD.y, 0.f);

  // ---- loop-invariant ragged-edge data (h = row&3 = rsub&3) ----
  const int  h  = rsub & 3;
  const bool j0 = (j == 0), j4 = (j == 4);
  const bool has3 = (j < 5);
  const float mA0 = (j0 && h > 0) ? NEGINF : 0.f;
  const float mA1 = (j0 && h > 1) ? NEGINF : 0.f;
  const float mA2 = (j0 && h > 2) ? NEGINF : 0.f;
  const float mC1 = (j4 && h < 1) ? NEGINF : 0.f;
  const float mC2 = (j4 && h < 2) ? NEGINF : 0.f;
  const float mC3 = (j4 && h < 3) ? NEGINF : 0.f;
  const int dA = 4 * j - h;
  const int dB = 4 * (j + 8) - h;
  const int dC = 4 * (j + 16) - h;

  const float4* cf  = (const float4*)conf;
  const float4* pbf = (const float4*)pred_boxes;

  float t_g = 0.f, t_l = 0.f;
  unsigned t_c = 0u, t_r = 0u;

  // ---- preload tile 0 ----
  int row = b * PP + loc * 32 + rsub;
  const unsigned ab0 = (81u * (unsigned)row) >> 2;
  float4 va = cf[ab0 + j];
  float4 vb = cf[ab0 + j + 8];
  float4 vc = has3 ? cf[ab0 + j + 16] : va;
  float4 pb = pbf[row];

  #pragma unroll
  for (int k = 0; k < NTILES_BLK; ++k) {
    // ---- prefetch tile k+1 (stays in flight during compute) ----
    float4 nva = va, nvb = vb, nvc = vc, npb = pb;
    if (k < NTILES_BLK - 1) {
      const int nrow = row + BLK_PER_IMG * 32;
      const unsigned nab = (81u * (unsigned)nrow) >> 2;
      nva = cf[nab + j];
      nvb = cf[nab + j + 8];
      if (has3) nvc = cf[nab + j + 16]; else nvc = nva;
      npb = pbf[nrow];
    }

    // ---- softmax stats (additive-mask trick) ----
    const float a0 = va.x + mA0, a1 = va.y + mA1, a2 = va.z + mA2, a3 = va.w;
    float mx = fmaxf(fmaxf(a0, a1), fmaxf(a2, a3));
    float s  = __expf(a0) + __expf(a1) + __expf(a2) + __expf(a3);
    mx = fmaxf(mx, fmaxf(fmaxf(vb.x, vb.y), fmaxf(vb.z, vb.w)));
    s += __expf(vb.x) + __expf(vb.y) + __expf(vb.z) + __expf(vb.w);
    if (has3) {
      const float e0 = vc.x, e1 = vc.y + mC1, e2 = vc.z + mC2, e3 = vc.w + mC3;
      mx = fmaxf(mx, fmaxf(fmaxf(e0, e1), fmaxf(e2, e3)));
      s += __expf(e0) + __expf(e1) + __expf(e2) + __expf(e3);
    }
    mx = fmaxf(mx, __shfl_xor(mx, 1));  s += __shfl_xor(s, 1);
    mx = fmaxf(mx, __shfl_xor(mx, 2));  s += __shfl_xor(s, 2);
    mx = fmaxf(mx, __shfl_xor(mx, 4));  s += __shfl_xor(s, 4);
    const float lse = __logf(s);
    const float smx = __expf(mx - lse);

    // ---- IoU match bits only (cheap, branchless) ----
    const float aa = fmaxf(pb.z - pb.x, 0.f) * fmaxf(pb.w - pb.y, 0.f);
    unsigned msk = 0u;      // row-level bits at (j+sh)
    unsigned mymt = 0u;     // this thread's 4 match bits (0..3)
    #define IOU_ONE(gb, ab, sh, bit)                                        \
    {                                                                       \
      const float ltx = fmaxf(pb.x, gb.x), lty = fmaxf(pb.y, gb.y);         \
      const float rbx = fminf(pb.z, gb.z), rby = fminf(pb.w, gb.w);         \
      const float inter = fmaxf(rbx - ltx, 0.f) * fmaxf(rby - lty, 0.f);    \
      const float uni = aa + ab - inter;                                    \
      const bool mt = inter > 0.5f * fmaxf(uni, 1e-9f);                     \
      msk  |= mt ? (1u << (j + sh)) : 0u;                                   \
      mymt |= mt ? (1u << bit) : 0u;                                        \
    }
    IOU_ONE(gA, abA, 0, 0)
    IOU_ONE(gB, abB, 8, 1)
    IOU_ONE(gC, abC, 16, 2)
    IOU_ONE(gD, abD, 24, 3)
    #undef IOU_ONE

    // full row match mask on every sub-thread
    msk |= __shfl_xor(msk, 1); msk |= __shfl_xor(msk, 2); msk |= __shfl_xor(msk, 4);

    if (j == 0) neg[row] = (msk != 0u) ? -1.0f : smx;

    // ---- matched-only work, skipped by whole waves with no matches ----
    if (__any(msk != 0u)) {
      float lsum = 0.f;
      #define SL1_ONE(gb, bit)                                              \
      if (mymt & (1u << bit)) {                                             \
        const float d0 = pb.x - gb.x, d1 = pb.y - gb.y;                     \
        const float d2 = pb.z - gb.z, d3 = pb.w - gb.w;                     \
        float sl = 0.f, ad;                                                 \
        ad = fabsf(d0); sl += (ad < 1.f) ? 0.5f * d0 * d0 : ad - 0.5f;      \
        ad = fabsf(d1); sl += (ad < 1.f) ? 0.5f * d1 * d1 : ad - 0.5f;      \
        ad = fabsf(d2); sl += (ad < 1.f) ? 0.5f * d2 * d2 : ad - 0.5f;      \
        ad = fabsf(d3); sl += (ad < 1.f) ? 0.5f * d3 * d3 : ad - 0.5f;      \
        lsum += sl * 0.25f;                                                 \
      }
      SL1_ONE(gA, 0)
      SL1_ONE(gB, 1)
      SL1_ONE(gC, 2)
      SL1_ONE(gD, 3)
      #undef SL1_ONE
      t_l += lsum;

      if (msk != 0u) {
        float gsum = 0.f;
        if (dA >= 0) gsum += va.x * (float)__popc(msk & s_gm[dA]);
        if (dA + 1 >= 0) gsum += va.y * (float)__popc(msk & s_gm[dA + 1]);
        if (dA + 2 >= 0) gsum += va.z * (float)__popc(msk & s_gm[dA + 2]);
        gsum += va.w * (float)__popc(msk & s_gm[dA + 3]);
        gsum += vb.x * (float)__popc(msk & s_gm[dB]);
        gsum += vb.y * (float)__popc(msk & s_gm[dB + 1]);
        gsum += vb.z * (float)__popc(msk & s_gm[dB + 2]);
        gsum += vb.w * (float)__popc(msk & s_gm[dB + 3]);
        if (has3) {
          gsum += vc.x * (float)__popc(msk & s_gm[dC]);
          if (dC + 1 < NC) gsum += vc.y * (float)__popc(msk & s_gm[dC + 1]);
          if (dC + 2 < NC) gsum += vc.z * (float)__popc(msk & s_gm[dC + 2]);
          if (dC + 3 < NC) gsum += vc.w * (float)__popc(msk & s_gm[dC + 3]);
        }
        t_g += gsum;
        if (j == 0) {
          const unsigned cnt = (unsigned)__popc(msk);
          t_g -= (float)cnt * lse;
          t_c += cnt;
          t_r += 1u;
        }
      }
    }

    va = nva; vb = nvb; vc = nvc; pb = npb;
    row += BLK_PER_IMG * 32;
  }

  // ---- wave butterfly -> LDS partials -> 4 atomics per block ----
  t_g += __shfl_xor(t_g, 1);  t_l += __shfl_xor(t_l, 1);  t_c += __shfl_xor(t_c, 1);  t_r += __shfl_xor(t_r, 1);
  t_g += __shfl_xor(t_g, 2);  t_l += __shfl_xor(t_l, 2);  t_c += __shfl_xor(t_c, 2);  t_r += __shfl_xor(t_r, 2);
  t_g += __shfl_xor(t_g, 4);  t_l += __shfl_xor(t_l, 4);  t_c += __shfl_xor(t_c, 4);  t_r += __shfl_xor(t_r, 4);
  t_g += __shfl_xor(t_g, 8);  t_l += __shfl_xor(t_l, 8);  t_c += __shfl_xor(t_c, 8);  t_r += __shfl_xor(t_r, 8);
  t_g += __shfl_xor(t_g, 16); t_l += __shfl_xor(t_l, 16); t_c += __shfl_xor(t_c, 16); t_r += __shfl_xor(t_r, 16);
  t_g += __shfl_xor(t_g, 32); t_l += __shfl_xor(t_l, 32); t_c += __shfl_xor(t_c, 32); t_r += __shfl_xor(t_r, 32);
  if (lane == 0) { pg[w] = t_g; pl[w] = t_l; pc[w] = t_c; pr[w] = t_r; }
  __syncthreads();
  if (tid == 0) {
    const unsigned c2 = pc[0] + pc[1] + pc[2] + pc[3];
    if (c2 > 0u) {
      atomicAdd(&acc->m[b],    pg[0] + pg[1] + pg[2] + pg[3]);
      atomicAdd(&acc->l[b],    pl[0] + pl[1] + pl[2] + pl[3]);
      atomicAdd(&acc->tot[b],  c2);
      atomicAdd(&acc->rowm[b], pr[0] + pr[1] + pr[2] + pr[3]);
    }
  }
}

// One block per image: 8192-bin LDS histogram -> threshold bin + remainder.
__global__ __launch_bounds__(256) void thresh_kernel(const float* __restrict__ neg,
                                                     Accs* __restrict__ acc) {
  const int b = blockIdx.x, tid = threadIdx.x;
  __shared__ unsigned hist[NBINS];
  __shared__ unsigned ps[256];
  __shared__ unsigned s_ch, s_cb;

  const unsigned total  = acc->tot[b];
  const unsigned nvalid = PP - acc->rowm[b];
  unsigned K = 3u * total;
  if (K > nvalid) K = nvalid;
  if (K == 0u) {
    if (tid == 0) { acc->tbin[b] = SENT; acc->rem[b] = 0u; }
    return;  // uniform
  }

  for (int i = tid; i < NBINS; i += 256) hist[i] = 0u;
  __syncthreads();

  const float4* nb = (const float4*)(neg + ((size_t)b << 15));
  for (int i = tid; i < PP / 4; i += 256) {
    const float4 v4 = nb[i];
    const float vv[4] = {v4.x, v4.y, v4.z, v4.w};
    #pragma unroll
    for (int q = 0; q < 4; ++q)
      if (vv[q] >= 0.f) atomicAdd(&hist[bin_of(__float_as_uint(vv[q]))], 1u);
  }
  __syncthreads();

  unsigned loc = 0;
  #pragma unroll
  for (int q = 0; q < NBINS / 256; ++q) loc += hist[tid * (NBINS / 256) + q];
  ps[tid] = loc;
  __syncthreads();
  for (int off = 1; off < 256; off <<= 1) {
    const unsigned v = (tid + off < 256) ? ps[tid + off] : 0u;
    __syncthreads();
    ps[tid] += v;
    __syncthreads();
  }
  {
    const unsigned above = (tid < 255) ? ps[tid + 1] : 0u;
    if (ps[tid] >= K && above < K) { s_ch = (unsigned)tid; s_cb = above; }
  }
  __syncthreads();
  const unsigned ch = s_ch, cb = s_cb;
  const int CH = NBINS / 256;  // 32
  if (tid < CH) ps[tid] = hist[ch * CH + tid];
  __syncthreads();
  for (int off = 1; off < CH; off <<= 1) {
    const unsigned v = (tid < CH && tid + off < CH) ? ps[tid + off] : 0u;
    __syncthreads();
    if (tid < CH) ps[tid] += v;
    __syncthreads();
  }
  if (tid < CH) {
    const unsigned above = cb + ((tid < CH - 1) ? ps[tid + 1] : 0u);
    if (above < K && cb + ps[tid] >= K) {
      acc->tbin[b] = ch * (unsigned)CH + (unsigned)tid;
      acc->rem[b]  = K - above;
    }
  }
}

// 16 blocks per image: sum log1p above threshold bin; collect bin-t candidates.
__global__ __launch_bounds__(256) void sum_kernel(const float* __restrict__ neg,
                                                  float* __restrict__ cand,
                                                  Accs* __restrict__ acc) {
  const int b  = blockIdx.x >> 4;
  const int sl = blockIdx.x & 15;
  const unsigned t = acc->tbin[b];
  const float4* nb = (const float4*)(neg + ((size_t)b << 15)) + sl * 512;
  float sum = 0.f;
  #pragma unroll
  for (int it = 0; it < 2; ++it) {
    const float4 v4 = nb[threadIdx.x + it * 256];
    const float vv[4] = {v4.x, v4.y, v4.z, v4.w};
    #pragma unroll
    for (int q = 0; q < 4; ++q) {
      const float v = vv[q];
      if (v >= 0.f) {
        const unsigned bin = (unsigned)bin_of(__float_as_uint(v));
        if (bin > t) {
          sum += log1pf(v);
        } else if (bin == t) {
          const unsigned idx = atomicAdd(&acc->candcnt[b], 1u);
          if (idx < CAND_CAP) cand[(size_t)b * CAND_CAP + idx] = v;
        }
      }
    }
  }
  sum += __shfl_xor(sum, 1);  sum += __shfl_xor(sum, 2);  sum += __shfl_xor(sum, 4);
  sum += __shfl_xor(sum, 8);  sum += __shfl_xor(sum, 16); sum += __shfl_xor(sum, 32);
  if ((threadIdx.x & 63) == 0 && sum != 0.f) atomicAdd(&acc->n[b], sum);
}

// One block per image: exact low-13-bit refinement inside the threshold bin,
// PLUS fused finish: the last block to complete computes the final scalar.
__global__ __launch_bounds__(256) void refine_kernel(const float* __restrict__ neg,
                                                     const float* __restrict__ cand,
                                                     Accs* __restrict__ acc,
                                                     float* __restrict__ out) {
  const int b = blockIdx.x, tid = threadIdx.x;
  __shared__ unsigned h2[NBINS];
  __shared__ unsigned ps[256];
  __shared__ unsigned s_thr, s_rem2;
  const unsigned t = acc->tbin[b];

  if (t != SENT) {
    const unsigned rem = acc->rem[b];
    const unsigned cc  = acc->candcnt[b];
    const bool fb = (cc > CAND_CAP);            // fallback: rescan neg row
    const int n_src = fb ? PP : (int)cc;
    const float* src = fb ? (neg + ((size_t)b << 15)) : (cand + (size_t)b * CAND_CAP);

    for (int i = tid; i < NBINS; i += 256) h2[i] = 0u;
    __syncthreads();
    for (int i = tid; i < n_src; i += 256) {
      const float v = src[i];
      if (fb) {
        if (!(v >= 0.f) || (unsigned)bin_of(__float_as_uint(v)) != t) continue;
      }
      atomicAdd(&h2[__float_as_uint(v) & LOWMASK], 1u);
    }
    __syncthreads();

    unsigned loc = 0;
    #pragma unroll
    for (int q = 0; q < NBINS / 256; ++q) loc += h2[tid * (NBINS / 256) + q];
    ps[tid] = loc;
    __syncthreads();
    for (int off = 1; off < 256; off <<= 1) {
      const unsigned v = (tid + off < 256) ? ps[tid + off] : 0u;
      __syncthreads();
      ps[tid] += v;
      __syncthreads();
    }
    {
      const unsigned above = (tid < 255) ? ps[tid + 1] : 0u;
      if (ps[tid] >= rem && above < rem) {
        unsigned c = above;
        const int CH = NBINS / 256;
        for (int q = CH - 1; q >= 0; --q) {
          const unsigned hb = h2[tid * CH + q];
          if (c + hb >= rem) { s_thr = (unsigned)(tid * CH + q); s_rem2 = rem - c; break; }
          c += hb;
        }
      }
    }
    __syncthreads();
    const unsigned thr = s_thr, rem2 = s_rem2;

    float sum = 0.f;
    for (int i = tid; i < n_src; i += 256) {
      const float v = src[i];
      if (fb) {
        if (!(v >= 0.f) || (unsigned)bin_of(__float_as_uint(v)) != t) continue;
      }
      if ((__float_as_uint(v) & LOWMASK) > thr) sum += log1pf(v);
    }
    sum += __shfl_xor(sum, 1);  sum += __shfl_xor(sum, 2);  sum += __shfl_xor(sum, 4);
    sum += __shfl_xor(sum, 8);  sum += __shfl_xor(sum, 16); sum += __shfl_xor(sum, 32);
    if ((tid & 63) == 0 && sum != 0.f) atomicAdd(&acc->n[b], sum);
    if (tid == 0 && rem2 > 0u) {
      const unsigned tb = BINBASE + (t << BINSHIFT) + thr;
      atomicAdd(&acc->n[b], (float)rem2 * log1pf(__uint_as_float(tb)));
    }
  }

  // ---- fused finish: last block across the grid computes the output ----
  __syncthreads();                 // drains this block's outstanding atomics
  if (tid == 0) {
    __threadfence();               // device-scope ordering before the counter
    const unsigned d = atomicAdd(&acc->done, 1u);
    if (d == BB - 1) {             // all other blocks' n[b] atomics completed
      float conf = 0.f, loc = 0.f;
      #pragma unroll
      for (int bb = 0; bb < BB; ++bb) {
        const float nb2 = atomicAdd(&acc->n[bb], 0.f);  // coherent RMW read
        conf += -acc->m[bb] + nb2;   // m/l/tot written by earlier kernels
        loc  += acc->l[bb];
      }
      out[0] = (conf + loc) / (float)acc->tot[BB - 1];
    }
  }
}

extern "C" void kernel_launch(void* const* d_in, const int* in_sizes, int n_in,
                              void* d_out, int out_size, void* d_ws, size_t ws_size,
                              hipStream_t stream) {
  const float* pred_boxes = (const float*)d_in[0];
  const float* conf       = (const float*)d_in[1];
  const float* gt_boxes   = (const float*)d_in[2];
  const int*   gt_labels  = (const int*)d_in[3];
  float* out = (float*)d_out;

  char* ws = (char*)d_ws;
  float* neg  = (float*)ws;                                       // 2 MB
  float* cand = (float*)(ws + (size_t)BB * PP * 4);               // 128 KB
  Accs*  acc  = (Accs*)(ws + (size_t)BB * PP * 4 + (size_t)BB * CAND_CAP * 4);

  hipLaunchKernelGGL(init_kernel, dim3(1), dim3(64), 0, stream, acc);
  hipLaunchKernelGGL(main_kernel, dim3(SM_BLOCKS), dim3(256), 0, stream,
                     pred_boxes, conf, gt_boxes, gt_labels, neg, acc);
  hipLaunchKernelGGL(thresh_kernel, dim3(BB), dim3(256), 0, stream, neg, acc);
  hipLaunchKernelGGL(sum_kernel, dim3(BB * 16), dim3(256), 0, stream, neg, cand, acc);
  hipLaunchKernelGGL(refine_kernel, dim3(BB), dim3(256), 0, stream, neg, cand, acc, out);
}

// Round 15
// 104.299 us; speedup vs baseline: 1.3229x; 1.3229x over previous
//
#include <hip/hip_runtime.h>
#include <hip/hip_bf16.h>
#include <math.h>

#define BB 16
#define PP 32768
#define GG 32
#define NC 81
#define BINSHIFT 13
#define NBINS 8192            // 32 KB LDS histogram
#define LOWMASK 0x1FFFu
#define BINBASE 0x3B800000u   // 2^-8 < min possible smx (1/81)
#define CAND_CAP 2048
#define SENT 0x7FFFFFFFu
#define SM_BLOCKS 2048
#define BLK_PER_IMG 128       // 2048 / 16
#define NEGINF (-3.0e38f)

struct Accs {
  float m[BB]; float l[BB]; float n[BB];
  unsigned tot[BB]; unsigned rowm[BB];
  unsigned tbin[BB]; unsigned rem[BB]; unsigned candcnt[BB];
};

__device__ __forceinline__ int bin_of(unsigned bits) {
  int bin = ((int)bits - (int)BINBASE) >> BINSHIFT;
  return bin < 0 ? 0 : (bin > NBINS - 1 ? NBINS - 1 : bin);
}

__global__ void init_kernel(Accs* __restrict__ acc) {
  const int t = threadIdx.x;
  if (t < BB) {
    acc->m[t] = 0.f; acc->l[t] = 0.f; acc->n[t] = 0.f;
    acc->tot[t] = 0u; acc->rowm[t] = 0u; acc->candcnt[t] = 0u;
  }
}

// Best measured configuration (round 9, 104.5 us total; main ~87 us).
// Fused softmax + IoU + LDS-popc gather, 1-tile-ahead prefetch,
// gt boxes in registers, wave-uniform skip of matched-only work.
__global__ __launch_bounds__(256) void main_kernel(
    const float* __restrict__ pred_boxes,   // (B,P,4)
    const float* __restrict__ conf,         // (B,P,C)
    const float* __restrict__ gt_boxes,     // (B,G,4)
    const int*   __restrict__ gt_labels,    // (B,G)
    float* __restrict__ neg,                // (B,P)
    Accs* __restrict__ acc)
{
  const int tid  = threadIdx.x;
  const int j    = tid & 7;                 // sub-thread within row
  const int rsub = tid >> 3;                // row within tile (0..31)
  const int b    = blockIdx.x / BLK_PER_IMG;
  const int loc  = blockIdx.x % BLK_PER_IMG;
  const int lane = tid & 63;
  const int w    = tid >> 6;

  __shared__ unsigned s_gm[NC + 3];         // label->gt-bitmask table
  __shared__ float pg[4], pl[4];
  __shared__ unsigned pc[4], pr[4];

  // ---- build per-image label-mask table (once per block) ----
  if (tid < NC + 3) s_gm[tid] = 0u;
  __syncthreads();
  if (tid < GG) atomicOr(&s_gm[gt_labels[b * GG + tid]], 1u << tid);
  __syncthreads();

  // ---- gt boxes in registers (4 per thread, j-layout) ----
  const float4* gtb = ((const float4*)gt_boxes) + b * GG;
  const float4 gA = gtb[j];
  const float4 gB = gtb[j + 8];
  const float4 gC = gtb[j + 16];
  const float4 gD = gtb[j + 24];
  const float abA = fmaxf(gA.z - gA.x, 0.f) * fmaxf(gA.w - gA.y, 0.f);
  const float abB = fmaxf(gB.z - gB.x, 0.f) * fmaxf(gB.w - gB.y, 0.f);
  const float abC = fmaxf(gC.z - gC.x, 0.f) * fmaxf(gC.w - gC.y, 0.f);
  const float abD = fmaxf(gD.z - gD.x, 0.f) * fmaxf(gD.w - gD.y, 0.f);

  // ---- loop-invariant ragged-edge data (h = row&3 = rsub&3) ----
  const int  h  = rsub & 3;
  const bool j0 = (j == 0), j4 = (j == 4);
  const bool has3 = (j < 5);
  const float mA0 = (j0 && h > 0) ? NEGINF : 0.f;
  const float mA1 = (j0 && h > 1) ? NEGINF : 0.f;
  const float mA2 = (j0 && h > 2) ? NEGINF : 0.f;
  const float mC1 = (j4 && h < 1) ? NEGINF : 0.f;
  const float mC2 = (j4 && h < 2) ? NEGINF : 0.f;
  const float mC3 = (j4 && h < 3) ? NEGINF : 0.f;
  const int dA = 4 * j - h;
  const int dB = 4 * (j + 8) - h;
  const int dC = 4 * (j + 16) - h;

  const float4* cf  = (const float4*)conf;
  const float4* pbf = (const float4*)pred_boxes;

  float t_g = 0.f, t_l = 0.f;
  unsigned t_c = 0u, t_r = 0u;

  // ---- preload tile 0 ----
  int row = b * PP + loc * 32 + rsub;
  const unsigned ab0 = (81u * (unsigned)row) >> 2;
  float4 va = cf[ab0 + j];
  float4 vb = cf[ab0 + j + 8];
  float4 vc = has3 ? cf[ab0 + j + 16] : va;
  float4 pb = pbf[row];

  #pragma unroll
  for (int k = 0; k < 8; ++k) {
    // ---- prefetch tile k+1 (stays in flight during compute) ----
    float4 nva = va, nvb = vb, nvc = vc, npb = pb;
    if (k < 7) {
      const int nrow = row + BLK_PER_IMG * 32;
      const unsigned nab = (81u * (unsigned)nrow) >> 2;
      nva = cf[nab + j];
      nvb = cf[nab + j + 8];
      if (has3) nvc = cf[nab + j + 16]; else nvc = nva;
      npb = pbf[nrow];
    }

    // ---- softmax stats (additive-mask trick) ----
    const float a0 = va.x + mA0, a1 = va.y + mA1, a2 = va.z + mA2, a3 = va.w;
    float mx = fmaxf(fmaxf(a0, a1), fmaxf(a2, a3));
    float s  = __expf(a0) + __expf(a1) + __expf(a2) + __expf(a3);
    mx = fmaxf(mx, fmaxf(fmaxf(vb.x, vb.y), fmaxf(vb.z, vb.w)));
    s += __expf(vb.x) + __expf(vb.y) + __expf(vb.z) + __expf(vb.w);
    if (has3) {
      const float e0 = vc.x, e1 = vc.y + mC1, e2 = vc.z + mC2, e3 = vc.w + mC3;
      mx = fmaxf(mx, fmaxf(fmaxf(e0, e1), fmaxf(e2, e3)));
      s += __expf(e0) + __expf(e1) + __expf(e2) + __expf(e3);
    }
    mx = fmaxf(mx, __shfl_xor(mx, 1));  s += __shfl_xor(s, 1);
    mx = fmaxf(mx, __shfl_xor(mx, 2));  s += __shfl_xor(s, 2);
    mx = fmaxf(mx, __shfl_xor(mx, 4));  s += __shfl_xor(s, 4);
    const float lse = __logf(s);
    const float smx = __expf(mx - lse);

    // ---- IoU match bits only (cheap, branchless) ----
    const float aa = fmaxf(pb.z - pb.x, 0.f) * fmaxf(pb.w - pb.y, 0.f);
    unsigned msk = 0u;      // row-level bits at (j+sh)
    unsigned mymt = 0u;     // this thread's 4 match bits (0..3)
    #define IOU_ONE(gb, ab, sh, bit)                                        \
    {                                                                       \
      const float ltx = fmaxf(pb.x, gb.x), lty = fmaxf(pb.y, gb.y);         \
      const float rbx = fminf(pb.z, gb.z), rby = fminf(pb.w, gb.w);         \
      const float inter = fmaxf(rbx - ltx, 0.f) * fmaxf(rby - lty, 0.f);    \
      const float uni = aa + ab - inter;                                    \
      const bool mt = inter > 0.5f * fmaxf(uni, 1e-9f);                     \
      msk  |= mt ? (1u << (j + sh)) : 0u;                                   \
      mymt |= mt ? (1u << bit) : 0u;                                        \
    }
    IOU_ONE(gA, abA, 0, 0)
    IOU_ONE(gB, abB, 8, 1)
    IOU_ONE(gC, abC, 16, 2)
    IOU_ONE(gD, abD, 24, 3)
    #undef IOU_ONE

    // full row match mask on every sub-thread
    msk |= __shfl_xor(msk, 1); msk |= __shfl_xor(msk, 2); msk |= __shfl_xor(msk, 4);

    if (j == 0) neg[row] = (msk != 0u) ? -1.0f : smx;

    // ---- matched-only work, skipped by whole waves with no matches ----
    if (__any(msk != 0u)) {
      float lsum = 0.f;
      #define SL1_ONE(gb, bit)                                              \
      if (mymt & (1u << bit)) {                                             \
        const float d0 = pb.x - gb.x, d1 = pb.y - gb.y;                     \
        const float d2 = pb.z - gb.z, d3 = pb.w - gb.w;                     \
        float sl = 0.f, ad;                                                 \
        ad = fabsf(d0); sl += (ad < 1.f) ? 0.5f * d0 * d0 : ad - 0.5f;      \
        ad = fabsf(d1); sl += (ad < 1.f) ? 0.5f * d1 * d1 : ad - 0.5f;      \
        ad = fabsf(d2); sl += (ad < 1.f) ? 0.5f * d2 * d2 : ad - 0.5f;      \
        ad = fabsf(d3); sl += (ad < 1.f) ? 0.5f * d3 * d3 : ad - 0.5f;      \
        lsum += sl * 0.25f;                                                 \
      }
      SL1_ONE(gA, 0)
      SL1_ONE(gB, 1)
      SL1_ONE(gC, 2)
      SL1_ONE(gD, 3)
      #undef SL1_ONE
      t_l += lsum;

      if (msk != 0u) {
        float gsum = 0.f;
        if (dA >= 0) gsum += va.x * (float)__popc(msk & s_gm[dA]);
        if (dA + 1 >= 0) gsum += va.y * (float)__popc(msk & s_gm[dA + 1]);
        if (dA + 2 >= 0) gsum += va.z * (float)__popc(msk & s_gm[dA + 2]);
        gsum += va.w * (float)__popc(msk & s_gm[dA + 3]);
        gsum += vb.x * (float)__popc(msk & s_gm[dB]);
        gsum += vb.y * (float)__popc(msk & s_gm[dB + 1]);
        gsum += vb.z * (float)__popc(msk & s_gm[dB + 2]);
        gsum += vb.w * (float)__popc(msk & s_gm[dB + 3]);
        if (has3) {
          gsum += vc.x * (float)__popc(msk & s_gm[dC]);
          if (dC + 1 < NC) gsum += vc.y * (float)__popc(msk & s_gm[dC + 1]);
          if (dC + 2 < NC) gsum += vc.z * (float)__popc(msk & s_gm[dC + 2]);
          if (dC + 3 < NC) gsum += vc.w * (float)__popc(msk & s_gm[dC + 3]);
        }
        t_g += gsum;
        if (j == 0) {
          const unsigned cnt = (unsigned)__popc(msk);
          t_g -= (float)cnt * lse;
          t_c += cnt;
          t_r += 1u;
        }
      }
    }

    va = nva; vb = nvb; vc = nvc; pb = npb;
    row += BLK_PER_IMG * 32;
  }

  // ---- wave butterfly -> LDS partials -> 4 atomics per block ----
  t_g += __shfl_xor(t_g, 1);  t_l += __shfl_xor(t_l, 1);  t_c += __shfl_xor(t_c, 1);  t_r += __shfl_xor(t_r, 1);
  t_g += __shfl_xor(t_g, 2);  t_l += __shfl_xor(t_l, 2);  t_c += __shfl_xor(t_c, 2);  t_r += __shfl_xor(t_r, 2);
  t_g += __shfl_xor(t_g, 4);  t_l += __shfl_xor(t_l, 4);  t_c += __shfl_xor(t_c, 4);  t_r += __shfl_xor(t_r, 4);
  t_g += __shfl_xor(t_g, 8);  t_l += __shfl_xor(t_l, 8);  t_c += __shfl_xor(t_c, 8);  t_r += __shfl_xor(t_r, 8);
  t_g += __shfl_xor(t_g, 16); t_l += __shfl_xor(t_l, 16); t_c += __shfl_xor(t_c, 16); t_r += __shfl_xor(t_r, 16);
  t_g += __shfl_xor(t_g, 32); t_l += __shfl_xor(t_l, 32); t_c += __shfl_xor(t_c, 32); t_r += __shfl_xor(t_r, 32);
  if (lane == 0) { pg[w] = t_g; pl[w] = t_l; pc[w] = t_c; pr[w] = t_r; }
  __syncthreads();
  if (tid == 0) {
    const unsigned c2 = pc[0] + pc[1] + pc[2] + pc[3];
    if (c2 > 0u) {
      atomicAdd(&acc->m[b],    pg[0] + pg[1] + pg[2] + pg[3]);
      atomicAdd(&acc->l[b],    pl[0] + pl[1] + pl[2] + pl[3]);
      atomicAdd(&acc->tot[b],  c2);
      atomicAdd(&acc->rowm[b], pr[0] + pr[1] + pr[2] + pr[3]);
    }
  }
}

// One block per image: 8192-bin LDS histogram -> threshold bin + remainder.
__global__ __launch_bounds__(256) void thresh_kernel(const float* __restrict__ neg,
                                                     Accs* __restrict__ acc) {
  const int b = blockIdx.x, tid = threadIdx.x;
  __shared__ unsigned hist[NBINS];
  __shared__ unsigned ps[256];
  __shared__ unsigned s_ch, s_cb;

  const unsigned total  = acc->tot[b];
  const unsigned nvalid = PP - acc->rowm[b];
  unsigned K = 3u * total;
  if (K > nvalid) K = nvalid;
  if (K == 0u) {
    if (tid == 0) { acc->tbin[b] = SENT; acc->rem[b] = 0u; }
    return;  // uniform
  }

  for (int i = tid; i < NBINS; i += 256) hist[i] = 0u;
  __syncthreads();

  const float4* nb = (const float4*)(neg + ((size_t)b << 15));
  for (int i = tid; i < PP / 4; i += 256) {
    const float4 v4 = nb[i];
    const float vv[4] = {v4.x, v4.y, v4.z, v4.w};
    #pragma unroll
    for (int q = 0; q < 4; ++q)
      if (vv[q] >= 0.f) atomicAdd(&hist[bin_of(__float_as_uint(vv[q]))], 1u);
  }
  __syncthreads();

  unsigned loc = 0;
  #pragma unroll
  for (int q = 0; q < NBINS / 256; ++q) loc += hist[tid * (NBINS / 256) + q];
  ps[tid] = loc;
  __syncthreads();
  for (int off = 1; off < 256; off <<= 1) {
    const unsigned v = (tid + off < 256) ? ps[tid + off] : 0u;
    __syncthreads();
    ps[tid] += v;
    __syncthreads();
  }
  {
    const unsigned above = (tid < 255) ? ps[tid + 1] : 0u;
    if (ps[tid] >= K && above < K) { s_ch = (unsigned)tid; s_cb = above; }
  }
  __syncthreads();
  const unsigned ch = s_ch, cb = s_cb;
  const int CH = NBINS / 256;  // 32
  if (tid < CH) ps[tid] = hist[ch * CH + tid];
  __syncthreads();
  for (int off = 1; off < CH; off <<= 1) {
    const unsigned v = (tid < CH && tid + off < CH) ? ps[tid + off] : 0u;
    __syncthreads();
    if (tid < CH) ps[tid] += v;
    __syncthreads();
  }
  if (tid < CH) {
    const unsigned above = cb + ((tid < CH - 1) ? ps[tid + 1] : 0u);
    if (above < K && cb + ps[tid] >= K) {
      acc->tbin[b] = ch * (unsigned)CH + (unsigned)tid;
      acc->rem[b]  = K - above;
    }
  }
}

// 16 blocks per image: sum log1p above threshold bin; collect bin-t candidates.
__global__ __launch_bounds__(256) void sum_kernel(const float* __restrict__ neg,
                                                  float* __restrict__ cand,
                                                  Accs* __restrict__ acc) {
  const int b  = blockIdx.x >> 4;
  const int sl = blockIdx.x & 15;
  const unsigned t = acc->tbin[b];
  const float4* nb = (const float4*)(neg + ((size_t)b << 15)) + sl * 512;
  float sum = 0.f;
  #pragma unroll
  for (int it = 0; it < 2; ++it) {
    const float4 v4 = nb[threadIdx.x + it * 256];
    const float vv[4] = {v4.x, v4.y, v4.z, v4.w};
    #pragma unroll
    for (int q = 0; q < 4; ++q) {
      const float v = vv[q];
      if (v >= 0.f) {
        const unsigned bin = (unsigned)bin_of(__float_as_uint(v));
        if (bin > t) {
          sum += log1pf(v);
        } else if (bin == t) {
          const unsigned idx = atomicAdd(&acc->candcnt[b], 1u);
          if (idx < CAND_CAP) cand[(size_t)b * CAND_CAP + idx] = v;
        }
      }
    }
  }
  sum += __shfl_xor(sum, 1);  sum += __shfl_xor(sum, 2);  sum += __shfl_xor(sum, 4);
  sum += __shfl_xor(sum, 8);  sum += __shfl_xor(sum, 16); sum += __shfl_xor(sum, 32);
  if ((threadIdx.x & 63) == 0 && sum != 0.f) atomicAdd(&acc->n[b], sum);
}

// One block per image: exact low-13-bit refinement inside the threshold bin.
__global__ __launch_bounds__(256) void refine_kernel(const float* __restrict__ neg,
                                                     const float* __restrict__ cand,
                                                     Accs* __restrict__ acc) {
  const int b = blockIdx.x, tid = threadIdx.x;
  __shared__ unsigned h2[NBINS];
  __shared__ unsigned ps[256];
  __shared__ unsigned s_thr, s_rem2;
  const unsigned t = acc->tbin[b];
  if (t == SENT) return;  // uniform
  const unsigned rem = acc->rem[b];
  const unsigned cc  = acc->candcnt[b];
  const bool fb = (cc > CAND_CAP);            // fallback: rescan neg row
  const int n_src = fb ? PP : (int)cc;
  const float* src = fb ? (neg + ((size_t)b << 15)) : (cand + (size_t)b * CAND_CAP);

  for (int i = tid; i < NBINS; i += 256) h2[i] = 0u;
  __syncthreads();
  for (int i = tid; i < n_src; i += 256) {
    const float v = src[i];
    if (fb) {
      if (!(v >= 0.f) || (unsigned)bin_of(__float_as_uint(v)) != t) continue;
    }
    atomicAdd(&h2[__float_as_uint(v) & LOWMASK], 1u);
  }
  __syncthreads();

  unsigned loc = 0;
  #pragma unroll
  for (int q = 0; q < NBINS / 256; ++q) loc += h2[tid * (NBINS / 256) + q];
  ps[tid] = loc;
  __syncthreads();
  for (int off = 1; off < 256; off <<= 1) {
    const unsigned v = (tid + off < 256) ? ps[tid + off] : 0u;
    __syncthreads();
    ps[tid] += v;
    __syncthreads();
  }
  {
    const unsigned above = (tid < 255) ? ps[tid + 1] : 0u;
    if (ps[tid] >= rem && above < rem) {
      unsigned c = above;
      const int CH = NBINS / 256;
      for (int q = CH - 1; q >= 0; --q) {
        const unsigned hb = h2[tid * CH + q];
        if (c + hb >= rem) { s_thr = (unsigned)(tid * CH + q); s_rem2 = rem - c; break; }
        c += hb;
      }
    }
  }
  __syncthreads();
  const unsigned thr = s_thr, rem2 = s_rem2;

  float sum = 0.f;
  for (int i = tid; i < n_src; i += 256) {
    const float v = src[i];
    if (fb) {
      if (!(v >= 0.f) || (unsigned)bin_of(__float_as_uint(v)) != t) continue;
    }
    if ((__float_as_uint(v) & LOWMASK) > thr) sum += log1pf(v);
  }
  sum += __shfl_xor(sum, 1);  sum += __shfl_xor(sum, 2);  sum += __shfl_xor(sum, 4);
  sum += __shfl_xor(sum, 8);  sum += __shfl_xor(sum, 16); sum += __shfl_xor(sum, 32);
  if ((tid & 63) == 0 && sum != 0.f) atomicAdd(&acc->n[b], sum);
  if (tid == 0 && rem2 > 0u) {
    const unsigned tb = BINBASE + (t << BINSHIFT) + thr;
    atomicAdd(&acc->n[b], (float)rem2 * log1pf(__uint_as_float(tb)));
  }
}

__global__ void finish_kernel(const Accs* __restrict__ acc, float* __restrict__ out) {
  if (threadIdx.x == 0) {
    float conf = 0.f, loc = 0.f;
    #pragma unroll
    for (int b = 0; b < BB; ++b) {
      conf += -acc->m[b] + acc->n[b];
      loc  += acc->l[b];
    }
    out[0] = (conf + loc) / (float)acc->tot[BB - 1];
  }
}

extern "C" void kernel_launch(void* const* d_in, const int* in_sizes, int n_in,
                              void* d_out, int out_size, void* d_ws, size_t ws_size,
                              hipStream_t stream) {
  const float* pred_boxes = (const float*)d_in[0];
  const float* conf       = (const float*)d_in[1];
  const float* gt_boxes   = (const float*)d_in[2];
  const int*   gt_labels  = (const int*)d_in[3];
  float* out = (float*)d_out;

  char* ws = (char*)d_ws;
  float* neg  = (float*)ws;                                       // 2 MB
  float* cand = (float*)(ws + (size_t)BB * PP * 4);               // 128 KB
  Accs*  acc  = (Accs*)(ws + (size_t)BB * PP * 4 + (size_t)BB * CAND_CAP * 4);

  hipLaunchKernelGGL(init_kernel, dim3(1), dim3(64), 0, stream, acc);
  hipLaunchKernelGGL(main_kernel, dim3(SM_BLOCKS), dim3(256), 0, stream,
                     pred_boxes, conf, gt_boxes, gt_labels, neg, acc);
  hipLaunchKernelGGL(thresh_kernel, dim3(BB), dim3(256), 0, stream, neg, acc);
  hipLaunchKernelGGL(sum_kernel, dim3(BB * 16), dim3(256), 0, stream, neg, cand, acc);
  hipLaunchKernelGGL(refine_kernel, dim3(BB), dim3(256), 0, stream, neg, cand, acc);
  hipLaunchKernelGGL(finish_kernel, dim3(1), dim3(64), 0, stream, acc, out);
}